// Round 2
// baseline (817.298 us; speedup 1.0000x reference)
//
#include <hip/hip_runtime.h>

typedef unsigned short u16;
typedef __bf16 bf16x8 __attribute__((ext_vector_type(8)));
typedef float f32x4 __attribute__((ext_vector_type(4)));

__device__ __forceinline__ u16 f2bf(float f) {
    unsigned int u = __builtin_bit_cast(unsigned int, f);
    u += 0x7fffu + ((u >> 16) & 1u);
    return (u16)(u >> 16);
}
__device__ __forceinline__ float bf2f(u16 b) {
    unsigned int u = ((unsigned int)b) << 16;
    return __builtin_bit_cast(float, u);
}
__device__ __forceinline__ void load_lds16(const void* g, void* l) {
    __builtin_amdgcn_global_load_lds((__attribute__((address_space(1))) void*)(g),
                                     (__attribute__((address_space(3))) void*)(l), 16, 0, 0);
}
__device__ __forceinline__ f32x4 mfma16(bf16x8 a, bf16x8 b, f32x4 c) {
    return __builtin_amdgcn_mfma_f32_16x16x32_bf16(a, b, c, 0, 0, 0);
}

// ---------- fp32 -> bf16 elementwise ----------
__global__ __launch_bounds__(256) void k_cvt_bf16(const float* __restrict__ in,
                                                  u16* __restrict__ out, int n4) {
    int i = blockIdx.x * 256 + threadIdx.x;
    if (i < n4) {
        float4 v = ((const float4*)in)[i];
        unsigned int lo = (unsigned int)f2bf(v.x) | ((unsigned int)f2bf(v.y) << 16);
        unsigned int hi = (unsigned int)f2bf(v.z) | ((unsigned int)f2bf(v.w) << 16);
        ((uint2*)out)[i] = make_uint2(lo, hi);
    }
}

// ---------- W[K][N] fp32 -> Wt[N][K] bf16 ----------
__global__ __launch_bounds__(256) void k_transpose_cvt(const float* __restrict__ W,
                                                       u16* __restrict__ Wt, int K, int N) {
    __shared__ u16 t[32][33];
    int tx = threadIdx.x & 31, ty = threadIdx.x >> 5;
    int n0 = blockIdx.x * 32, k0 = blockIdx.y * 32;
#pragma unroll
    for (int i = 0; i < 4; i++)
        t[ty + i * 8][tx] = f2bf(W[(size_t)(k0 + ty + i * 8) * N + n0 + tx]);
    __syncthreads();
#pragma unroll
    for (int i = 0; i < 4; i++)
        Wt[(size_t)(n0 + ty + i * 8) * K + k0 + tx] = t[tx][ty + i * 8];
}

// ---------- V[2048][8*128] bf16 -> Vt[8][128][2048] bf16 ----------
__global__ __launch_bounds__(256) void k_transpose_v(const u16* __restrict__ V,
                                                     u16* __restrict__ Vt) {
    __shared__ u16 t[32][33];
    int tx = threadIdx.x & 31, ty = threadIdx.x >> 5;
    int t0 = blockIdx.x * 32, d0 = blockIdx.y * 32, kh = blockIdx.z;
#pragma unroll
    for (int i = 0; i < 4; i++)
        t[ty + i * 8][tx] = V[(size_t)(t0 + ty + i * 8) * 1024 + kh * 128 + d0 + tx];
    __syncthreads();
#pragma unroll
    for (int i = 0; i < 4; i++)
        Vt[((size_t)kh * 128 + d0 + ty + i * 8) * 2048 + t0 + tx] = t[tx][ty + i * 8];
}

// ---------- RoPE in place on bf16 [T][nheads*128], pairs (d, d+64) ----------
__global__ __launch_bounds__(256) void k_rope(u16* __restrict__ X,
                                              const float* __restrict__ cosT,
                                              const float* __restrict__ sinT, int nheads) {
    int idx = blockIdx.x * 256 + threadIdx.x;  // t*nheads*64 threads total
    int d = idx & 63;
    int h = (idx >> 6) & (nheads - 1);
    int tp = idx / (nheads * 64);
    size_t base = (size_t)tp * nheads * 128 + h * 128 + d;
    float q1 = bf2f(X[base]), q2 = bf2f(X[base + 64]);
    float c = cosT[tp * 64 + d], s = sinT[tp * 64 + d];
    X[base] = f2bf(q1 * c - q2 * s);
    X[base + 64] = f2bf(q2 * c + q1 * s);
}

// ---------- GEMM: C[M][N] = A[M][K] * Bt[N][K]^T  (bf16 in, fp32 accum) ----------
// m97 structure: 128x128 tile, BK=32, 4 waves 2x2, global_load_lds width 16.
// OutT = u16 (bf16 store) or float (fp32 store, for d_out).
template <typename OutT>
__global__ __launch_bounds__(256) void k_gemm_bt(const u16* __restrict__ A,
                                                 const u16* __restrict__ B,
                                                 OutT* __restrict__ C, int M, int N, int K) {
    __shared__ u16 sA[128 * 32];
    __shared__ u16 sB[128 * 32];
    const int tid = threadIdx.x;
    const int wave = tid >> 6, lane = tid & 63;
    const int m0 = blockIdx.y << 7, n0 = blockIdx.x << 7;
    const int wr = (wave >> 1) << 6, wc = (wave & 1) << 6;
    const int r0 = tid >> 2;               // staging row (0..63)
    const int kb = (tid & 3) << 4;         // staging byte offset in row
    const int fr = lane & 15;              // fragment row/col
    const int fkb = (lane >> 4) << 4;      // fragment k byte offset

    f32x4 acc[4][4] = {};
    const char* gA = (const char*)A + ((size_t)(m0 + r0) * K) * 2 + kb;
    const char* gB = (const char*)B + ((size_t)(n0 + r0) * K) * 2 + kb;
    char* lA = (char*)sA + wave * 1024;
    char* lB = (char*)sB + wave * 1024;
    const size_t rowskip = (size_t)64 * K * 2;

    for (int k0 = 0; k0 < K; k0 += 32) {
        load_lds16(gA, lA);
        load_lds16(gA + rowskip, lA + 4096);
        load_lds16(gB, lB);
        load_lds16(gB + rowskip, lB + 4096);
        gA += 64; gB += 64;
        __syncthreads();
        bf16x8 af[4], bg[4];
#pragma unroll
        for (int i = 0; i < 4; i++)
            af[i] = *(const bf16x8*)((const char*)sA + ((wr + i * 16 + fr) << 6) + fkb);
#pragma unroll
        for (int j = 0; j < 4; j++)
            bg[j] = *(const bf16x8*)((const char*)sB + ((wc + j * 16 + fr) << 6) + fkb);
#pragma unroll
        for (int i = 0; i < 4; i++)
#pragma unroll
            for (int j = 0; j < 4; j++)
                acc[i][j] = mfma16(af[i], bg[j], acc[i][j]);
        __syncthreads();
    }
    const int rr = (lane >> 4) << 2, cc = lane & 15;
#pragma unroll
    for (int i = 0; i < 4; i++)
#pragma unroll
        for (int j = 0; j < 4; j++)
#pragma unroll
            for (int r = 0; r < 4; r++) {
                float v = acc[i][j][r];
                OutT sv;
                if constexpr (sizeof(OutT) == 2) sv = f2bf(v); else sv = v;
                C[(size_t)(m0 + wr + i * 16 + rr + r) * N + (n0 + wc + j * 16 + cc)] = sv;
            }
}

// ---------- causal GQA flash attention ----------
// grid (T/128, 32 heads), 4 waves; wave owns 32 q-rows; KV tiles of 64.
__global__ __launch_bounds__(256, 1) void k_attn(const u16* __restrict__ Q,
                                                 const u16* __restrict__ K,
                                                 const u16* __restrict__ Vt,
                                                 u16* __restrict__ Y) {
    __shared__ u16 kt[64 * 128];   // K tile, rows 256B, XOR-swizzled
    __shared__ u16 vt[128 * 64];   // V^T tile, rows 128B, XOR-swizzled
    __shared__ u16 pl[4 * 32 * 64];  // per-wave P, rows 128B, XOR-swizzled
    const int tid = threadIdx.x;
    const int wave = tid >> 6, lane = tid & 63;
    const int l15 = lane & 15, l4 = lane >> 4;
    const int h = blockIdx.y, kh = h >> 2;
    const int q0 = blockIdx.x << 7;
    const int qw = q0 + wave * 32;
    const float scale = 0.08838834764831845f;  // 1/sqrt(128)

    // Q fragments straight from global (row-contiguous)
    bf16x8 aq[2][4];
#pragma unroll
    for (int tr = 0; tr < 2; tr++)
#pragma unroll
        for (int kf = 0; kf < 4; kf++)
            aq[tr][kf] = *(const bf16x8*)(Q + (size_t)(qw + tr * 16 + l15) * 4096 +
                                          h * 128 + kf * 32 + l4 * 8);

    f32x4 o[2][8] = {};
    float mrow[2][4], lrow[2][4];
#pragma unroll
    for (int tr = 0; tr < 2; tr++)
#pragma unroll
        for (int rg = 0; rg < 4; rg++) { mrow[tr][rg] = -1e30f; lrow[tr][rg] = 0.f; }

    char* ktb = (char*)kt;
    char* vtb = (char*)vt;
    char* plb = (char*)pl + wave * 4096;
    const int nkt = (blockIdx.x + 1) * 2;

    for (int it = 0; it < nkt; ++it) {
        const int kbase = it << 6;
        // stage K tile (pre-swizzled global source, linear LDS dest)
#pragma unroll
        for (int p = 0; p < 4; p++) {
            int ol = wave * 4096 + p * 1024 + lane * 16;
            int key = ol >> 8, db = ol & 255;
            int src = db ^ ((key & 7) << 4);
            load_lds16((const char*)K + ((size_t)(kbase + key) * 1024 + kh * 128) * 2 + src,
                       ktb + wave * 4096 + p * 1024);
        }
        // stage V^T tile
#pragma unroll
        for (int p = 0; p < 4; p++) {
            int ol = wave * 4096 + p * 1024 + lane * 16;
            int d = ol >> 7, kb2 = ol & 127;
            int src = kb2 ^ ((d & 7) << 4);
            load_lds16((const char*)Vt + ((size_t)(kh * 128 + d) * 2048 + kbase) * 2 + src,
                       vtb + wave * 4096 + p * 1024);
        }
        __syncthreads();

        // S = Q K^T : 2 q-tiles x 4 key-tiles
        f32x4 s[2][4];
#pragma unroll
        for (int tc = 0; tc < 4; tc++) {
            bf16x8 bk[4];
            const int key = tc * 16 + l15;
            const int swz = (key & 7) << 4;
#pragma unroll
            for (int kf = 0; kf < 4; kf++)
                bk[kf] = *(const bf16x8*)(ktb + key * 256 + ((kf * 64 + l4 * 16) ^ swz));
#pragma unroll
            for (int tr = 0; tr < 2; tr++) {
                f32x4 sv = {0.f, 0.f, 0.f, 0.f};
#pragma unroll
                for (int kf = 0; kf < 4; kf++) sv = mfma16(aq[tr][kf], bk[kf], sv);
                s[tr][tc] = sv;
            }
        }
        // online softmax (wave-parallel: 16-lane groups share a row set)
#pragma unroll
        for (int tr = 0; tr < 2; tr++) {
#pragma unroll
            for (int rg = 0; rg < 4; rg++) {
                const int qrow = qw + tr * 16 + l4 * 4 + rg;
                float mx = -1e30f;
#pragma unroll
                for (int tc = 0; tc < 4; tc++) {
                    float v = s[tr][tc][rg] * scale;
                    int key = kbase + tc * 16 + l15;
                    v = (key > qrow) ? -1e30f : v;
                    s[tr][tc][rg] = v;
                    mx = fmaxf(mx, v);
                }
                mx = fmaxf(mx, __shfl_xor(mx, 1));
                mx = fmaxf(mx, __shfl_xor(mx, 2));
                mx = fmaxf(mx, __shfl_xor(mx, 4));
                mx = fmaxf(mx, __shfl_xor(mx, 8));
                const float mold = mrow[tr][rg];
                const float mnew = fmaxf(mold, mx);
                const float corr = __expf(mold - mnew);
                mrow[tr][rg] = mnew;
                float rs = 0.f;
#pragma unroll
                for (int tc = 0; tc < 4; tc++) {
                    float p = __expf(s[tr][tc][rg] - mnew);
                    s[tr][tc][rg] = p;
                    rs += p;
                }
                rs += __shfl_xor(rs, 1);
                rs += __shfl_xor(rs, 2);
                rs += __shfl_xor(rs, 4);
                rs += __shfl_xor(rs, 8);
                lrow[tr][rg] = lrow[tr][rg] * corr + rs;
#pragma unroll
                for (int dc = 0; dc < 8; dc++) o[tr][dc][rg] *= corr;
            }
        }
        // P -> per-wave LDS (swizzled), bf16
#pragma unroll
        for (int tr = 0; tr < 2; tr++)
#pragma unroll
            for (int rg = 0; rg < 4; rg++) {
                const int row = tr * 16 + l4 * 4 + rg;
                const int swz = (row & 7) << 4;
#pragma unroll
                for (int tc = 0; tc < 4; tc++) {
                    const int cb = (tc * 16 + l15) * 2;
                    *(u16*)(plb + row * 128 + (cb ^ swz)) = f2bf(s[tr][tc][rg]);
                }
            }
        // P A-fragments
        bf16x8 pa[2][2];
#pragma unroll
        for (int tr = 0; tr < 2; tr++) {
            const int row = tr * 16 + l15;
            const int swz = (row & 7) << 4;
#pragma unroll
            for (int kf = 0; kf < 2; kf++)
                pa[tr][kf] = *(const bf16x8*)(plb + row * 128 + ((kf * 64 + l4 * 16) ^ swz));
        }
        // O += P V
#pragma unroll
        for (int dc = 0; dc < 8; dc++) {
            bf16x8 vf[2];
            const int d = dc * 16 + l15;
            const int swz = (d & 7) << 4;
#pragma unroll
            for (int kf = 0; kf < 2; kf++)
                vf[kf] = *(const bf16x8*)(vtb + d * 128 + ((kf * 64 + l4 * 16) ^ swz));
#pragma unroll
            for (int tr = 0; tr < 2; tr++) {
                o[tr][dc] = mfma16(pa[tr][0], vf[0], o[tr][dc]);
                o[tr][dc] = mfma16(pa[tr][1], vf[1], o[tr][dc]);
            }
        }
        __syncthreads();
    }
    // epilogue: normalize and store
#pragma unroll
    for (int tr = 0; tr < 2; tr++)
#pragma unroll
        for (int rg = 0; rg < 4; rg++) {
            const float inv = 1.f / lrow[tr][rg];
            const int row = qw + tr * 16 + l4 * 4 + rg;
#pragma unroll
            for (int dc = 0; dc < 8; dc++)
                Y[(size_t)row * 4096 + h * 128 + dc * 16 + l15] = f2bf(o[tr][dc][rg] * inv);
        }
}

extern "C" void kernel_launch(void* const* d_in, const int* in_sizes, int n_in,
                              void* d_out, int out_size, void* d_ws, size_t ws_size,
                              hipStream_t stream) {
    const float* x  = (const float*)d_in[0];
    const float* rc = (const float*)d_in[1];
    const float* rs = (const float*)d_in[2];
    const float* Wq = (const float*)d_in[3];
    const float* Wk = (const float*)d_in[4];
    const float* Wv = (const float*)d_in[5];
    const float* Wo = (const float*)d_in[6];
    float* out = (float*)d_out;  // reference output dtype is float32

    char* ws = (char*)d_ws;
    u16* xb = (u16*)(ws);                  // 16 MiB
    u16* Wt = (u16*)(ws + 16777216);       // 32 MiB (reused per-W)
    u16* Qb = (u16*)(ws + 50331648);       // 16 MiB
    u16* Kb = (u16*)(ws + 67108864);       // 4 MiB
    u16* Vb = (u16*)(ws + 71303168);       // 4 MiB
    u16* Vtb = (u16*)(ws + 75497472);      // 4 MiB
    u16* Y  = (u16*)(ws + 79691776);       // 16 MiB  (total 92 MiB)

    // x -> bf16
    k_cvt_bf16<<<8192, 256, 0, stream>>>(x, xb, 2097152);
    // Q = x Wq
    k_transpose_cvt<<<dim3(128, 128), 256, 0, stream>>>(Wq, Wt, 4096, 4096);
    k_gemm_bt<u16><<<dim3(32, 16), 256, 0, stream>>>(xb, Wt, Qb, 2048, 4096, 4096);
    // K = x Wk
    k_transpose_cvt<<<dim3(32, 128), 256, 0, stream>>>(Wk, Wt, 4096, 1024);
    k_gemm_bt<u16><<<dim3(8, 16), 256, 0, stream>>>(xb, Wt, Kb, 2048, 1024, 4096);
    // V = x Wv
    k_transpose_cvt<<<dim3(32, 128), 256, 0, stream>>>(Wv, Wt, 4096, 1024);
    k_gemm_bt<u16><<<dim3(8, 16), 256, 0, stream>>>(xb, Wt, Vb, 2048, 1024, 4096);
    // RoPE
    k_rope<<<16384, 256, 0, stream>>>(Qb, rc, rs, 32);
    k_rope<<<4096, 256, 0, stream>>>(Kb, rc, rs, 8);
    // V -> V^T per head
    k_transpose_v<<<dim3(64, 4, 8), 256, 0, stream>>>(Vb, Vtb);
    // attention
    k_attn<<<dim3(16, 32), 256, 0, stream>>>(Qb, Kb, Vtb, Y);
    // out = y Wo  (fp32 output)
    k_transpose_cvt<<<dim3(128, 128), 256, 0, stream>>>(Wo, Wt, 4096, 4096);
    k_gemm_bt<float><<<dim3(32, 16), 256, 0, stream>>>(Y, Wt, out, 2048, 4096, 4096);
}

// Round 3
// 626.076 us; speedup vs baseline: 1.3054x; 1.3054x over previous
//
#include <hip/hip_runtime.h>

typedef unsigned short u16;
typedef __bf16 bf16x8 __attribute__((ext_vector_type(8)));
typedef float f32x4 __attribute__((ext_vector_type(4)));

__device__ __forceinline__ u16 f2bf(float f) {
    unsigned int u = __builtin_bit_cast(unsigned int, f);
    u += 0x7fffu + ((u >> 16) & 1u);
    return (u16)(u >> 16);
}
__device__ __forceinline__ float bf2f(u16 b) {
    unsigned int u = ((unsigned int)b) << 16;
    return __builtin_bit_cast(float, u);
}
__device__ __forceinline__ void load_lds16(const void* g, void* l) {
    __builtin_amdgcn_global_load_lds((__attribute__((address_space(1))) void*)(g),
                                     (__attribute__((address_space(3))) void*)(l), 16, 0, 0);
}
__device__ __forceinline__ f32x4 mfma16(bf16x8 a, bf16x8 b, f32x4 c) {
    return __builtin_amdgcn_mfma_f32_16x16x32_bf16(a, b, c, 0, 0, 0);
}

// ---------- fp32 -> bf16 elementwise ----------
__global__ __launch_bounds__(256) void k_cvt_bf16(const float* __restrict__ in,
                                                  u16* __restrict__ out, int n4) {
    int i = blockIdx.x * 256 + threadIdx.x;
    if (i < n4) {
        float4 v = ((const float4*)in)[i];
        unsigned int lo = (unsigned int)f2bf(v.x) | ((unsigned int)f2bf(v.y) << 16);
        unsigned int hi = (unsigned int)f2bf(v.z) | ((unsigned int)f2bf(v.w) << 16);
        ((uint2*)out)[i] = make_uint2(lo, hi);
    }
}

// ---------- W[K][N] fp32 -> Wt[N][K] bf16 ----------
__global__ __launch_bounds__(256) void k_transpose_cvt(const float* __restrict__ W,
                                                       u16* __restrict__ Wt, int K, int N) {
    __shared__ u16 t[32][33];
    int tx = threadIdx.x & 31, ty = threadIdx.x >> 5;
    int n0 = blockIdx.x * 32, k0 = blockIdx.y * 32;
#pragma unroll
    for (int i = 0; i < 4; i++)
        t[ty + i * 8][tx] = f2bf(W[(size_t)(k0 + ty + i * 8) * N + n0 + tx]);
    __syncthreads();
#pragma unroll
    for (int i = 0; i < 4; i++)
        Wt[(size_t)(n0 + ty + i * 8) * K + k0 + tx] = t[tx][ty + i * 8];
}

// ---------- V (cols 1024..2047 of KV[2048][2048]) -> Vt[8][128][2048] ----------
__global__ __launch_bounds__(256) void k_transpose_v(const u16* __restrict__ KV,
                                                     u16* __restrict__ Vt) {
    __shared__ u16 t[32][33];
    int tx = threadIdx.x & 31, ty = threadIdx.x >> 5;
    int t0 = blockIdx.x * 32, d0 = blockIdx.y * 32, kh = blockIdx.z;
#pragma unroll
    for (int i = 0; i < 4; i++)
        t[ty + i * 8][tx] = KV[(size_t)(t0 + ty + i * 8) * 2048 + 1024 + kh * 128 + d0 + tx];
    __syncthreads();
#pragma unroll
    for (int i = 0; i < 4; i++)
        Vt[((size_t)kh * 128 + d0 + ty + i * 8) * 2048 + t0 + tx] = t[tx][ty + i * 8];
}

// ---------- RoPE in place on bf16 [T][rowstride], pairs (d, d+64) ----------
__global__ __launch_bounds__(256) void k_rope(u16* __restrict__ X,
                                              const float* __restrict__ cosT,
                                              const float* __restrict__ sinT, int nheads,
                                              int rowstride) {
    int idx = blockIdx.x * 256 + threadIdx.x;  // T*nheads*64 threads total
    int d = idx & 63;
    int h = (idx >> 6) & (nheads - 1);
    int tp = idx / (nheads * 64);
    size_t base = (size_t)tp * rowstride + h * 128 + d;
    float q1 = bf2f(X[base]), q2 = bf2f(X[base + 64]);
    float c = cosT[tp * 64 + d], s = sinT[tp * 64 + d];
    X[base] = f2bf(q1 * c - q2 * s);
    X[base + 64] = f2bf(q2 * c + q1 * s);
}

// ---------- GEMM: C[M][N] = A[M][K] * Bt[N][K]^T  (bf16 in, fp32 accum) ----------
// m97 structure: 128x128 tile, BK=32, 4 waves 2x2, global_load_lds width 16.
template <typename OutT>
__global__ __launch_bounds__(256) void k_gemm_bt(const u16* __restrict__ A,
                                                 const u16* __restrict__ B,
                                                 OutT* __restrict__ C, int M, int N, int K) {
    __shared__ u16 sA[128 * 32];
    __shared__ u16 sB[128 * 32];
    const int tid = threadIdx.x;
    const int wave = tid >> 6, lane = tid & 63;
    const int m0 = blockIdx.y << 7, n0 = blockIdx.x << 7;
    const int wr = (wave >> 1) << 6, wc = (wave & 1) << 6;
    const int r0 = tid >> 2;
    const int kb = (tid & 3) << 4;
    const int fr = lane & 15;
    const int fkb = (lane >> 4) << 4;

    f32x4 acc[4][4] = {};
    const char* gA = (const char*)A + ((size_t)(m0 + r0) * K) * 2 + kb;
    const char* gB = (const char*)B + ((size_t)(n0 + r0) * K) * 2 + kb;
    char* lA = (char*)sA + wave * 1024;
    char* lB = (char*)sB + wave * 1024;
    const size_t rowskip = (size_t)64 * K * 2;

    for (int k0 = 0; k0 < K; k0 += 32) {
        load_lds16(gA, lA);
        load_lds16(gA + rowskip, lA + 4096);
        load_lds16(gB, lB);
        load_lds16(gB + rowskip, lB + 4096);
        gA += 64; gB += 64;
        __syncthreads();
        bf16x8 af[4], bg[4];
#pragma unroll
        for (int i = 0; i < 4; i++)
            af[i] = *(const bf16x8*)((const char*)sA + ((wr + i * 16 + fr) << 6) + fkb);
#pragma unroll
        for (int j = 0; j < 4; j++)
            bg[j] = *(const bf16x8*)((const char*)sB + ((wc + j * 16 + fr) << 6) + fkb);
#pragma unroll
        for (int i = 0; i < 4; i++)
#pragma unroll
            for (int j = 0; j < 4; j++)
                acc[i][j] = mfma16(af[i], bg[j], acc[i][j]);
        __syncthreads();
    }
    const int rr = (lane >> 4) << 2, cc = lane & 15;
#pragma unroll
    for (int i = 0; i < 4; i++)
#pragma unroll
        for (int j = 0; j < 4; j++)
#pragma unroll
            for (int r = 0; r < 4; r++) {
                float v = acc[i][j][r];
                OutT sv;
                if constexpr (sizeof(OutT) == 2) sv = f2bf(v); else sv = v;
                C[(size_t)(m0 + wr + i * 16 + rr + r) * N + (n0 + wc + j * 16 + cc)] = sv;
            }
}

// ---------- causal GQA flash attention, work-balanced ----------
// grid (16, 32 heads): block p handles q-tiles p and 31-p (64 rows each) ->
// uniform 33 KV-tile units per block. 4 waves x 16 q-rows.
__global__ __launch_bounds__(256, 2) void k_attn(const u16* __restrict__ Q,
                                                 const u16* __restrict__ K,   // KV, stride 2048
                                                 const u16* __restrict__ Vt,
                                                 u16* __restrict__ Y) {
    __shared__ u16 kt[64 * 128];    // K tile, rows 256B, XOR-swizzled
    __shared__ u16 vt[128 * 64];    // V^T tile, rows 128B, XOR-swizzled
    __shared__ u16 pl[4 * 16 * 64]; // per-wave P, rows 128B, XOR-swizzled
    const int tid = threadIdx.x;
    const int wave = tid >> 6, lane = tid & 63;
    const int l15 = lane & 15, l4 = lane >> 4;
    const int h = blockIdx.y, kh = h >> 2;
    const float scale = 0.08838834764831845f;  // 1/sqrt(128)

    char* ktb = (char*)kt;
    char* vtb = (char*)vt;
    char* plb = (char*)pl + wave * 2048;

#pragma unroll 1
    for (int qsel = 0; qsel < 2; qsel++) {
        const int qt = qsel == 0 ? blockIdx.x : 31 - blockIdx.x;
        const int qw = qt * 64 + wave * 16;

        bf16x8 aq[4];
#pragma unroll
        for (int kf = 0; kf < 4; kf++)
            aq[kf] = *(const bf16x8*)(Q + (size_t)(qw + l15) * 4096 + h * 128 + kf * 32 + l4 * 8);

        f32x4 o[8] = {};
        float mrow[4], lrow[4];
#pragma unroll
        for (int rg = 0; rg < 4; rg++) { mrow[rg] = -1e30f; lrow[rg] = 0.f; }

        const int nkt = qt + 1;
        for (int it = 0; it < nkt; ++it) {
            const int kbase = it << 6;
            // stage K tile (pre-swizzled global source, linear LDS dest)
#pragma unroll
            for (int p = 0; p < 4; p++) {
                int ol = wave * 4096 + p * 1024 + lane * 16;
                int key = ol >> 8, db = ol & 255;
                int src = db ^ ((key & 7) << 4);
                load_lds16((const char*)K + ((size_t)(kbase + key) * 2048 + kh * 128) * 2 + src,
                           ktb + wave * 4096 + p * 1024);
            }
            // stage V^T tile
#pragma unroll
            for (int p = 0; p < 4; p++) {
                int ol = wave * 4096 + p * 1024 + lane * 16;
                int d = ol >> 7, kb2 = ol & 127;
                int src = kb2 ^ ((d & 7) << 4);
                load_lds16((const char*)Vt + ((size_t)(kh * 128 + d) * 2048 + kbase) * 2 + src,
                           vtb + wave * 4096 + p * 1024);
            }
            __syncthreads();

            // S = Q K^T : 4 key-tiles
            f32x4 s[4];
#pragma unroll
            for (int tc = 0; tc < 4; tc++) {
                bf16x8 bk[4];
                const int key = tc * 16 + l15;
                const int swz = (key & 7) << 4;
#pragma unroll
                for (int kf = 0; kf < 4; kf++)
                    bk[kf] = *(const bf16x8*)(ktb + key * 256 + ((kf * 64 + l4 * 16) ^ swz));
                f32x4 sv = {0.f, 0.f, 0.f, 0.f};
#pragma unroll
                for (int kf = 0; kf < 4; kf++) sv = mfma16(aq[kf], bk[kf], sv);
                s[tc] = sv;
            }
            // online softmax (wave-parallel: 16-lane groups share a row set)
#pragma unroll
            for (int rg = 0; rg < 4; rg++) {
                const int qrow = qw + l4 * 4 + rg;
                float mx = -1e30f;
#pragma unroll
                for (int tc = 0; tc < 4; tc++) {
                    float v = s[tc][rg] * scale;
                    int key = kbase + tc * 16 + l15;
                    v = (key > qrow) ? -1e30f : v;
                    s[tc][rg] = v;
                    mx = fmaxf(mx, v);
                }
                mx = fmaxf(mx, __shfl_xor(mx, 1));
                mx = fmaxf(mx, __shfl_xor(mx, 2));
                mx = fmaxf(mx, __shfl_xor(mx, 4));
                mx = fmaxf(mx, __shfl_xor(mx, 8));
                const float mold = mrow[rg];
                const float mnew = fmaxf(mold, mx);
                const float corr = __expf(mold - mnew);
                mrow[rg] = mnew;
                float rs = 0.f;
#pragma unroll
                for (int tc = 0; tc < 4; tc++) {
                    float p = __expf(s[tc][rg] - mnew);
                    s[tc][rg] = p;
                    rs += p;
                }
                rs += __shfl_xor(rs, 1);
                rs += __shfl_xor(rs, 2);
                rs += __shfl_xor(rs, 4);
                rs += __shfl_xor(rs, 8);
                lrow[rg] = lrow[rg] * corr + rs;
#pragma unroll
                for (int dc = 0; dc < 8; dc++) o[dc][rg] *= corr;
            }
            // P -> per-wave LDS (swizzled), bf16
#pragma unroll
            for (int rg = 0; rg < 4; rg++) {
                const int row = l4 * 4 + rg;
                const int swz = (row & 7) << 4;
#pragma unroll
                for (int tc = 0; tc < 4; tc++) {
                    const int cb = (tc * 16 + l15) * 2;
                    *(u16*)(plb + row * 128 + (cb ^ swz)) = f2bf(s[tc][rg]);
                }
            }
            // P A-fragments
            bf16x8 pa[2];
            {
                const int row = l15;
                const int swz = (row & 7) << 4;
#pragma unroll
                for (int kf = 0; kf < 2; kf++)
                    pa[kf] = *(const bf16x8*)(plb + row * 128 + ((kf * 64 + l4 * 16) ^ swz));
            }
            // O += P V
#pragma unroll
            for (int dc = 0; dc < 8; dc++) {
                bf16x8 vf[2];
                const int d = dc * 16 + l15;
                const int swz = (d & 7) << 4;
#pragma unroll
                for (int kf = 0; kf < 2; kf++)
                    vf[kf] = *(const bf16x8*)(vtb + d * 128 + ((kf * 64 + l4 * 16) ^ swz));
                o[dc] = mfma16(pa[0], vf[0], o[dc]);
                o[dc] = mfma16(pa[1], vf[1], o[dc]);
            }
            __syncthreads();
        }
        // epilogue: normalize and store
#pragma unroll
        for (int rg = 0; rg < 4; rg++) {
            const float inv = 1.f / lrow[rg];
            const int row = qw + l4 * 4 + rg;
#pragma unroll
            for (int dc = 0; dc < 8; dc++)
                Y[(size_t)row * 4096 + h * 128 + dc * 16 + l15] = f2bf(o[dc][rg] * inv);
        }
        __syncthreads();  // LDS reuse across qsel
    }
}

extern "C" void kernel_launch(void* const* d_in, const int* in_sizes, int n_in,
                              void* d_out, int out_size, void* d_ws, size_t ws_size,
                              hipStream_t stream) {
    const float* x  = (const float*)d_in[0];
    const float* rc = (const float*)d_in[1];
    const float* rs = (const float*)d_in[2];
    const float* Wq = (const float*)d_in[3];
    const float* Wk = (const float*)d_in[4];
    const float* Wv = (const float*)d_in[5];
    const float* Wo = (const float*)d_in[6];
    float* out = (float*)d_out;  // reference output dtype is float32

    char* ws = (char*)d_ws;
    u16* xb  = (u16*)(ws);                 // 16 MiB
    u16* Wt  = (u16*)(ws + 16777216);      // 32 MiB (reused per-W; KV uses 16.8 MB)
    u16* Qb  = (u16*)(ws + 50331648);      // 16 MiB
    u16* KV  = (u16*)(ws + 67108864);      // 8.4 MB: [2048][2048] = [K | V]
    u16* Vtb = (u16*)(ws + 75497472);      // 4 MiB
    u16* Y   = (u16*)(ws + 79691776);      // 16 MiB  (total 92 MiB)

    // x -> bf16
    k_cvt_bf16<<<8192, 256, 0, stream>>>(x, xb, 2097152);
    // Q = x Wq
    k_transpose_cvt<<<dim3(128, 128), 256, 0, stream>>>(Wq, Wt, 4096, 4096);
    k_gemm_bt<u16><<<dim3(32, 16), 256, 0, stream>>>(xb, Wt, Qb, 2048, 4096, 4096);
    // KV = x [Wk | Wv]   (fused: Wt rows 0..1023 = Wk^T, 1024..2047 = Wv^T)
    k_transpose_cvt<<<dim3(32, 128), 256, 0, stream>>>(Wk, Wt, 4096, 1024);
    k_transpose_cvt<<<dim3(32, 128), 256, 0, stream>>>(Wv, Wt + (size_t)1024 * 4096, 4096, 1024);
    k_gemm_bt<u16><<<dim3(16, 16), 256, 0, stream>>>(xb, Wt, KV, 2048, 2048, 4096);
    // RoPE
    k_rope<<<16384, 256, 0, stream>>>(Qb, rc, rs, 32, 4096);
    k_rope<<<4096, 256, 0, stream>>>(KV, rc, rs, 8, 2048);
    // V -> V^T per head
    k_transpose_v<<<dim3(64, 4, 8), 256, 0, stream>>>(KV, Vtb);
    // attention (work-balanced pairing)
    k_attn<<<dim3(16, 32), 256, 0, stream>>>(Qb, KV, Vtb, Y);
    // out = y Wo  (fp32 output)
    k_transpose_cvt<<<dim3(128, 128), 256, 0, stream>>>(Wo, Wt, 4096, 4096);
    k_gemm_bt<float><<<dim3(32, 16), 256, 0, stream>>>(Y, Wt, out, 2048, 4096, 4096);
}

// Round 4
// 570.358 us; speedup vs baseline: 1.4330x; 1.0977x over previous
//
#include <hip/hip_runtime.h>

typedef unsigned short u16;
typedef __bf16 bf16x8 __attribute__((ext_vector_type(8)));
typedef float f32x4 __attribute__((ext_vector_type(4)));

__device__ __forceinline__ u16 f2bf(float f) {
    unsigned int u = __builtin_bit_cast(unsigned int, f);
    u += 0x7fffu + ((u >> 16) & 1u);
    return (u16)(u >> 16);
}
__device__ __forceinline__ float bf2f(u16 b) {
    unsigned int u = ((unsigned int)b) << 16;
    return __builtin_bit_cast(float, u);
}
__device__ __forceinline__ void load_lds16(const void* g, void* l) {
    __builtin_amdgcn_global_load_lds((__attribute__((address_space(1))) void*)(g),
                                     (__attribute__((address_space(3))) void*)(l), 16, 0, 0);
}
__device__ __forceinline__ f32x4 mfma16(bf16x8 a, bf16x8 b, f32x4 c) {
    return __builtin_amdgcn_mfma_f32_16x16x32_bf16(a, b, c, 0, 0, 0);
}

// ---------- fp32 -> bf16 elementwise ----------
__global__ __launch_bounds__(256) void k_cvt_bf16(const float* __restrict__ in,
                                                  u16* __restrict__ out, int n4) {
    int i = blockIdx.x * 256 + threadIdx.x;
    if (i < n4) {
        float4 v = ((const float4*)in)[i];
        unsigned int lo = (unsigned int)f2bf(v.x) | ((unsigned int)f2bf(v.y) << 16);
        unsigned int hi = (unsigned int)f2bf(v.z) | ((unsigned int)f2bf(v.w) << 16);
        ((uint2*)out)[i] = make_uint2(lo, hi);
    }
}

// ---------- W[K][N] fp32 -> Wt[N][K] bf16 ----------
__global__ __launch_bounds__(256) void k_transpose_cvt(const float* __restrict__ W,
                                                       u16* __restrict__ Wt, int K, int N) {
    __shared__ u16 t[32][33];
    int tx = threadIdx.x & 31, ty = threadIdx.x >> 5;
    int n0 = blockIdx.x * 32, k0 = blockIdx.y * 32;
#pragma unroll
    for (int i = 0; i < 4; i++)
        t[ty + i * 8][tx] = f2bf(W[(size_t)(k0 + ty + i * 8) * N + n0 + tx]);
    __syncthreads();
#pragma unroll
    for (int i = 0; i < 4; i++)
        Wt[(size_t)(n0 + ty + i * 8) * K + k0 + tx] = t[tx][ty + i * 8];
}

// ---------- V (cols 5120..6143 of QKV[2048][6144]) -> Vt[8][128][2048] ----------
__global__ __launch_bounds__(256) void k_transpose_v(const u16* __restrict__ QKV,
                                                     u16* __restrict__ Vt) {
    __shared__ u16 t[32][33];
    int tx = threadIdx.x & 31, ty = threadIdx.x >> 5;
    int t0 = blockIdx.x * 32, d0 = blockIdx.y * 32, kh = blockIdx.z;
#pragma unroll
    for (int i = 0; i < 4; i++)
        t[ty + i * 8][tx] = QKV[(size_t)(t0 + ty + i * 8) * 6144 + 5120 + kh * 128 + d0 + tx];
    __syncthreads();
#pragma unroll
    for (int i = 0; i < 4; i++)
        Vt[((size_t)kh * 128 + d0 + ty + i * 8) * 2048 + t0 + tx] = t[tx][ty + i * 8];
}

// ---------- fused RoPE over 40 heads (32 Q + 8 K) on QKV[2048][6144] ----------
__global__ __launch_bounds__(256) void k_rope2(u16* __restrict__ QKV,
                                               const float* __restrict__ cosT,
                                               const float* __restrict__ sinT) {
    int idx = blockIdx.x * 256 + threadIdx.x;  // 2048*40*64 threads
    int d = idx & 63;
    int h = (idx >> 6) % 40;
    int tp = idx / (40 * 64);
    int col = h < 32 ? h * 128 : 4096 + (h - 32) * 128;
    size_t base = (size_t)tp * 6144 + col + d;
    float q1 = bf2f(QKV[base]), q2 = bf2f(QKV[base + 64]);
    float c = cosT[tp * 64 + d], s = sinT[tp * 64 + d];
    QKV[base] = f2bf(q1 * c - q2 * s);
    QKV[base + 64] = f2bf(q2 * c + q1 * s);
}

// ---------- GEMM: C[M][N] = A[M][K] * Bt[N][K]^T  (bf16 in, fp32 accum) ----------
// m97 structure: 128x128 tile, BK=32, 4 waves 2x2, global_load_lds width 16,
// + T1 XCD-bijective block swizzle.
template <typename OutT>
__global__ __launch_bounds__(256) void k_gemm_bt(const u16* __restrict__ A,
                                                 const u16* __restrict__ B,
                                                 OutT* __restrict__ C, int M, int N, int K) {
    __shared__ u16 sA[128 * 32];
    __shared__ u16 sB[128 * 32];
    const int tid = threadIdx.x;
    const int wave = tid >> 6, lane = tid & 63;
    // XCD-bijective swizzle (m204): contiguous tile chunk per XCD
    const int gx = (int)gridDim.x;
    const int nwg = gx * (int)gridDim.y;
    const int orig = (int)blockIdx.y * gx + (int)blockIdx.x;
    const int qq = nwg >> 3, rr8 = nwg & 7;
    const int xcd = orig & 7, bidx = orig >> 3;
    const int swz = (xcd < rr8 ? xcd * (qq + 1) : rr8 * (qq + 1) + (xcd - rr8) * qq) + bidx;
    const int m0 = (swz / gx) << 7;
    const int n0 = (swz % gx) << 7;
    const int wr = (wave >> 1) << 6, wc = (wave & 1) << 6;
    const int r0 = tid >> 2;
    const int kb = (tid & 3) << 4;
    const int fr = lane & 15;
    const int fkb = (lane >> 4) << 4;

    f32x4 acc[4][4] = {};
    const char* gA = (const char*)A + ((size_t)(m0 + r0) * K) * 2 + kb;
    const char* gB = (const char*)B + ((size_t)(n0 + r0) * K) * 2 + kb;
    char* lA = (char*)sA + wave * 1024;
    char* lB = (char*)sB + wave * 1024;
    const size_t rowskip = (size_t)64 * K * 2;

    for (int k0 = 0; k0 < K; k0 += 32) {
        load_lds16(gA, lA);
        load_lds16(gA + rowskip, lA + 4096);
        load_lds16(gB, lB);
        load_lds16(gB + rowskip, lB + 4096);
        gA += 64; gB += 64;
        __syncthreads();
        bf16x8 af[4], bg[4];
#pragma unroll
        for (int i = 0; i < 4; i++)
            af[i] = *(const bf16x8*)((const char*)sA + ((wr + i * 16 + fr) << 6) + fkb);
#pragma unroll
        for (int j = 0; j < 4; j++)
            bg[j] = *(const bf16x8*)((const char*)sB + ((wc + j * 16 + fr) << 6) + fkb);
#pragma unroll
        for (int i = 0; i < 4; i++)
#pragma unroll
            for (int j = 0; j < 4; j++)
                acc[i][j] = mfma16(af[i], bg[j], acc[i][j]);
        __syncthreads();
    }
    const int rr = (lane >> 4) << 2, cc = lane & 15;
#pragma unroll
    for (int i = 0; i < 4; i++)
#pragma unroll
        for (int j = 0; j < 4; j++)
#pragma unroll
            for (int r = 0; r < 4; r++) {
                float v = acc[i][j][r];
                OutT sv;
                if constexpr (sizeof(OutT) == 2) sv = f2bf(v); else sv = v;
                C[(size_t)(m0 + wr + i * 16 + rr + r) * N + (n0 + wc + j * 16 + cc)] = sv;
            }
}

// ---------- causal GQA flash attention, work-balanced ----------
// grid (16, 32 heads): block p handles q-tiles p and 31-p (64 rows each).
// Q/K live in QKV[2048][6144]: Q at col h*128, K at col 4096+kh*128.
__global__ __launch_bounds__(256, 2) void k_attn(const u16* __restrict__ Q,
                                                 const u16* __restrict__ K,   // QKV+4096
                                                 const u16* __restrict__ Vt,
                                                 u16* __restrict__ Y) {
    __shared__ u16 kt[64 * 128];    // K tile, rows 256B, XOR-swizzled
    __shared__ u16 vt[128 * 64];    // V^T tile, rows 128B, XOR-swizzled
    __shared__ u16 pl[4 * 16 * 64]; // per-wave P, rows 128B, XOR-swizzled
    const int tid = threadIdx.x;
    const int wave = tid >> 6, lane = tid & 63;
    const int l15 = lane & 15, l4 = lane >> 4;
    const int h = blockIdx.y, kh = h >> 2;
    const float scale = 0.08838834764831845f;  // 1/sqrt(128)

    char* ktb = (char*)kt;
    char* vtb = (char*)vt;
    char* plb = (char*)pl + wave * 2048;

#pragma unroll 1
    for (int qsel = 0; qsel < 2; qsel++) {
        const int qt = qsel == 0 ? blockIdx.x : 31 - blockIdx.x;
        const int qw = qt * 64 + wave * 16;

        bf16x8 aq[4];
#pragma unroll
        for (int kf = 0; kf < 4; kf++)
            aq[kf] = *(const bf16x8*)(Q + (size_t)(qw + l15) * 6144 + h * 128 + kf * 32 + l4 * 8);

        f32x4 o[8] = {};
        float mrow[4], lrow[4];
#pragma unroll
        for (int rg = 0; rg < 4; rg++) { mrow[rg] = -1e30f; lrow[rg] = 0.f; }

        const int nkt = qt + 1;
        for (int it = 0; it < nkt; ++it) {
            const int kbase = it << 6;
            // stage K tile (pre-swizzled global source, linear LDS dest)
#pragma unroll
            for (int p = 0; p < 4; p++) {
                int ol = wave * 4096 + p * 1024 + lane * 16;
                int key = ol >> 8, db = ol & 255;
                int src = db ^ ((key & 7) << 4);
                load_lds16((const char*)K + ((size_t)(kbase + key) * 6144 + kh * 128) * 2 + src,
                           ktb + wave * 4096 + p * 1024);
            }
            // stage V^T tile
#pragma unroll
            for (int p = 0; p < 4; p++) {
                int ol = wave * 4096 + p * 1024 + lane * 16;
                int d = ol >> 7, kb2 = ol & 127;
                int src = kb2 ^ ((d & 7) << 4);
                load_lds16((const char*)Vt + ((size_t)(kh * 128 + d) * 2048 + kbase) * 2 + src,
                           vtb + wave * 4096 + p * 1024);
            }
            __syncthreads();

            // S = Q K^T : 4 key-tiles
            f32x4 s[4];
#pragma unroll
            for (int tc = 0; tc < 4; tc++) {
                bf16x8 bk[4];
                const int key = tc * 16 + l15;
                const int swz = (key & 7) << 4;
#pragma unroll
                for (int kf = 0; kf < 4; kf++)
                    bk[kf] = *(const bf16x8*)(ktb + key * 256 + ((kf * 64 + l4 * 16) ^ swz));
                f32x4 sv = {0.f, 0.f, 0.f, 0.f};
#pragma unroll
                for (int kf = 0; kf < 4; kf++) sv = mfma16(aq[kf], bk[kf], sv);
                s[tc] = sv;
            }
            // online softmax (wave-parallel: 16-lane groups share a row set)
#pragma unroll
            for (int rg = 0; rg < 4; rg++) {
                const int qrow = qw + l4 * 4 + rg;
                float mx = -1e30f;
#pragma unroll
                for (int tc = 0; tc < 4; tc++) {
                    float v = s[tc][rg] * scale;
                    int key = kbase + tc * 16 + l15;
                    v = (key > qrow) ? -1e30f : v;
                    s[tc][rg] = v;
                    mx = fmaxf(mx, v);
                }
                mx = fmaxf(mx, __shfl_xor(mx, 1));
                mx = fmaxf(mx, __shfl_xor(mx, 2));
                mx = fmaxf(mx, __shfl_xor(mx, 4));
                mx = fmaxf(mx, __shfl_xor(mx, 8));
                const float mold = mrow[rg];
                const float mnew = fmaxf(mold, mx);
                const float corr = __expf(mold - mnew);
                mrow[rg] = mnew;
                float rs = 0.f;
#pragma unroll
                for (int tc = 0; tc < 4; tc++) {
                    float p = __expf(s[tc][rg] - mnew);
                    s[tc][rg] = p;
                    rs += p;
                }
                rs += __shfl_xor(rs, 1);
                rs += __shfl_xor(rs, 2);
                rs += __shfl_xor(rs, 4);
                rs += __shfl_xor(rs, 8);
                lrow[rg] = lrow[rg] * corr + rs;
#pragma unroll
                for (int dc = 0; dc < 8; dc++) o[dc][rg] *= corr;
            }
            // P -> per-wave LDS (swizzled), bf16
#pragma unroll
            for (int rg = 0; rg < 4; rg++) {
                const int row = l4 * 4 + rg;
                const int swz = (row & 7) << 4;
#pragma unroll
                for (int tc = 0; tc < 4; tc++) {
                    const int cb = (tc * 16 + l15) * 2;
                    *(u16*)(plb + row * 128 + (cb ^ swz)) = f2bf(s[tc][rg]);
                }
            }
            // P A-fragments
            bf16x8 pa[2];
            {
                const int row = l15;
                const int swz = (row & 7) << 4;
#pragma unroll
                for (int kf = 0; kf < 2; kf++)
                    pa[kf] = *(const bf16x8*)(plb + row * 128 + ((kf * 64 + l4 * 16) ^ swz));
            }
            // O += P V
#pragma unroll
            for (int dc = 0; dc < 8; dc++) {
                bf16x8 vf[2];
                const int d = dc * 16 + l15;
                const int swz = (d & 7) << 4;
#pragma unroll
                for (int kf = 0; kf < 2; kf++)
                    vf[kf] = *(const bf16x8*)(vtb + d * 128 + ((kf * 64 + l4 * 16) ^ swz));
                o[dc] = mfma16(pa[0], vf[0], o[dc]);
                o[dc] = mfma16(pa[1], vf[1], o[dc]);
            }
            __syncthreads();
        }
        // epilogue: normalize and store
#pragma unroll
        for (int rg = 0; rg < 4; rg++) {
            const float inv = 1.f / lrow[rg];
            const int row = qw + l4 * 4 + rg;
#pragma unroll
            for (int dc = 0; dc < 8; dc++)
                Y[(size_t)row * 4096 + h * 128 + dc * 16 + l15] = f2bf(o[dc][rg] * inv);
        }
        __syncthreads();  // LDS reuse across qsel
    }
}

extern "C" void kernel_launch(void* const* d_in, const int* in_sizes, int n_in,
                              void* d_out, int out_size, void* d_ws, size_t ws_size,
                              hipStream_t stream) {
    const float* x  = (const float*)d_in[0];
    const float* rc = (const float*)d_in[1];
    const float* rs = (const float*)d_in[2];
    const float* Wq = (const float*)d_in[3];
    const float* Wk = (const float*)d_in[4];
    const float* Wv = (const float*)d_in[5];
    const float* Wo = (const float*)d_in[6];
    float* out = (float*)d_out;  // reference output dtype is float32

    char* ws = (char*)d_ws;
    u16* xb  = (u16*)(ws);                 // 16 MiB: x bf16; later reused as Y
    u16* Wt  = (u16*)(ws + 16777216);      // 48 MiB: [Wq|Wk|Wv]^T (later Wo^T)
    u16* QKV = (u16*)(ws + 67108864);      // 24 MiB: [2048][6144] = [Q|K|V]
    u16* Vtb = (u16*)(ws + 92274688);      // 4 MiB: [8][128][2048]
    u16* Y   = xb;                         // reuse (xb dead after QKV GEMM)

    // x -> bf16
    k_cvt_bf16<<<8192, 256, 0, stream>>>(x, xb, 2097152);
    // fused weight transpose: Wt rows 0..4095 = Wq^T, 4096..5119 = Wk^T, 5120..6143 = Wv^T
    k_transpose_cvt<<<dim3(128, 128), 256, 0, stream>>>(Wq, Wt, 4096, 4096);
    k_transpose_cvt<<<dim3(32, 128), 256, 0, stream>>>(Wk, Wt + (size_t)4096 * 4096, 4096, 1024);
    k_transpose_cvt<<<dim3(32, 128), 256, 0, stream>>>(Wv, Wt + (size_t)5120 * 4096, 4096, 1024);
    // QKV = x [Wq|Wk|Wv]  (768 blocks = 3/CU)
    k_gemm_bt<u16><<<dim3(48, 16), 256, 0, stream>>>(xb, Wt, QKV, 2048, 6144, 4096);
    // fused RoPE over 40 heads
    k_rope2<<<20480, 256, 0, stream>>>(QKV, rc, rs);
    // V -> V^T per head
    k_transpose_v<<<dim3(64, 4, 8), 256, 0, stream>>>(QKV, Vtb);
    // attention (work-balanced pairing); Y overwrites xb region
    k_attn<<<dim3(16, 32), 256, 0, stream>>>(QKV, QKV + 4096, Vtb, Y);
    // out = y Wo  (fp32 output)
    k_transpose_cvt<<<dim3(128, 128), 256, 0, stream>>>(Wo, Wt, 4096, 4096);
    k_gemm_bt<float><<<dim3(32, 16), 256, 0, stream>>>(Y, Wt, out, 2048, 4096, 4096);
}

// Round 6
// 527.972 us; speedup vs baseline: 1.5480x; 1.0803x over previous
//
#include <hip/hip_runtime.h>

typedef unsigned short u16;
typedef __bf16 bf16x8 __attribute__((ext_vector_type(8)));
typedef float f32x4 __attribute__((ext_vector_type(4)));

__device__ __forceinline__ u16 f2bf(float f) {
    unsigned int u = __builtin_bit_cast(unsigned int, f);
    u += 0x7fffu + ((u >> 16) & 1u);
    return (u16)(u >> 16);
}
__device__ __forceinline__ float bf2f(u16 b) {
    unsigned int u = ((unsigned int)b) << 16;
    return __builtin_bit_cast(float, u);
}
__device__ __forceinline__ void load_lds16(const void* g, void* l) {
    __builtin_amdgcn_global_load_lds((__attribute__((address_space(1))) void*)(g),
                                     (__attribute__((address_space(3))) void*)(l), 16, 0, 0);
}
__device__ __forceinline__ f32x4 mfma16(bf16x8 a, bf16x8 b, f32x4 c) {
    return __builtin_amdgcn_mfma_f32_16x16x32_bf16(a, b, c, 0, 0, 0);
}

// ---------- fp32 -> bf16 elementwise ----------
__global__ __launch_bounds__(256) void k_cvt_bf16(const float* __restrict__ in,
                                                  u16* __restrict__ out, int n4) {
    int i = blockIdx.x * 256 + threadIdx.x;
    if (i < n4) {
        float4 v = ((const float4*)in)[i];
        unsigned int lo = (unsigned int)f2bf(v.x) | ((unsigned int)f2bf(v.y) << 16);
        unsigned int hi = (unsigned int)f2bf(v.z) | ((unsigned int)f2bf(v.w) << 16);
        ((uint2*)out)[i] = make_uint2(lo, hi);
    }
}

// ---------- W[K][N] fp32 -> Wt[N][K] bf16 ----------
__global__ __launch_bounds__(256) void k_transpose_cvt(const float* __restrict__ W,
                                                       u16* __restrict__ Wt, int K, int N) {
    __shared__ u16 t[32][33];
    int tx = threadIdx.x & 31, ty = threadIdx.x >> 5;
    int n0 = blockIdx.x * 32, k0 = blockIdx.y * 32;
#pragma unroll
    for (int i = 0; i < 4; i++)
        t[ty + i * 8][tx] = f2bf(W[(size_t)(k0 + ty + i * 8) * N + n0 + tx]);
    __syncthreads();
#pragma unroll
    for (int i = 0; i < 4; i++)
        Wt[(size_t)(n0 + ty + i * 8) * K + k0 + tx] = t[tx][ty + i * 8];
}

// ---------- V (cols 5120..6143 of QKV[2048][6144]) -> Vt[8][128][2048] ----------
__global__ __launch_bounds__(256) void k_transpose_v(const u16* __restrict__ QKV,
                                                     u16* __restrict__ Vt) {
    __shared__ u16 t[32][33];
    int tx = threadIdx.x & 31, ty = threadIdx.x >> 5;
    int t0 = blockIdx.x * 32, d0 = blockIdx.y * 32, kh = blockIdx.z;
#pragma unroll
    for (int i = 0; i < 4; i++)
        t[ty + i * 8][tx] = QKV[(size_t)(t0 + ty + i * 8) * 6144 + 5120 + kh * 128 + d0 + tx];
    __syncthreads();
#pragma unroll
    for (int i = 0; i < 4; i++)
        Vt[((size_t)kh * 128 + d0 + ty + i * 8) * 2048 + t0 + tx] = t[tx][ty + i * 8];
}

// ---------- fused RoPE over 40 heads (32 Q + 8 K) on QKV[2048][6144] ----------
__global__ __launch_bounds__(256) void k_rope2(u16* __restrict__ QKV,
                                               const float* __restrict__ cosT,
                                               const float* __restrict__ sinT) {
    int idx = blockIdx.x * 256 + threadIdx.x;  // 2048*40*64 threads
    int d = idx & 63;
    int h = (idx >> 6) % 40;
    int tp = idx / (40 * 64);
    int col = h < 32 ? h * 128 : 4096 + (h - 32) * 128;
    size_t base = (size_t)tp * 6144 + col + d;
    float q1 = bf2f(QKV[base]), q2 = bf2f(QKV[base + 64]);
    float c = cosT[tp * 64 + d], s = sinT[tp * 64 + d];
    QKV[base] = f2bf(q1 * c - q2 * s);
    QKV[base + 64] = f2bf(q2 * c + q1 * s);
}

// ---------- 256x256 8-phase GEMM: C[M][N] = A[M][K] * Bt[N][K]^T ----------
// T2 (LDS XOR-swizzle) + T3/T4 (phase interleave, counted vmcnt, raw barriers)
// + T5 (setprio) + T1 (XCD-bijective block swizzle).
// 512 threads = 8 waves (2M x 4N); per-wave output 128x64; BK=64 in 2 k-halves.
// LDS 128 KiB: A[2buf][2kh][256][32] bf16 | B[2buf][2kh][256][32] bf16.

#define STAGE(G, base0, ldsOff, kt, kh)                                                     \
    {                                                                                       \
        _Pragma("unroll") for (int p = 0; p < 2; p++) {                                     \
            int o = p * 8192 + o0;                                                          \
            int row = o >> 6;                                                               \
            int kb = (o & 48) ^ (((row >> 1) & 3) << 4);                                    \
            load_lds16((const char*)(G) +                                                   \
                           ((size_t)(base0 + row) * K + (kt) * 64 + (kh) * 32) * 2 + kb,    \
                       lb + (ldsOff) + p * 8192 + waveB);                                   \
        }                                                                                   \
    }
#define LDA(kh, bufv)                                                                       \
    _Pragma("unroll") for (int fm = 0; fm < 8; fm++) {                                      \
        int row = wmBase + fm * 16 + l15;                                                   \
        af[fm] = *(const bf16x8*)(lb + (bufv) * 32768 + (kh) * 16384 + row * 64 +           \
                                  ((l4 * 16) ^ (((row >> 1) & 3) << 4)));                   \
    }
#define LDB(fn, kh, bufv, dst)                                                              \
    {                                                                                       \
        int row = wnBase + (fn) * 16 + l15;                                                 \
        dst = *(const bf16x8*)(lb + 65536 + (bufv) * 32768 + (kh) * 16384 + row * 64 +      \
                               ((l4 * 16) ^ (((row >> 1) & 3) << 4)));                      \
    }
#define MFMA2(fnA, fnB)                                                                     \
    __builtin_amdgcn_s_setprio(1);                                                          \
    _Pragma("unroll") for (int fm = 0; fm < 8; fm++) {                                      \
        acc[fm][fnA] = mfma16(af[fm], b0, acc[fm][fnA]);                                    \
        acc[fm][fnB] = mfma16(af[fm], b1, acc[fm][fnB]);                                    \
    }                                                                                       \
    __builtin_amdgcn_s_setprio(0);

template <typename OutT>
__global__ __launch_bounds__(512, 2) void k_gemm256(const u16* __restrict__ A,
                                                    const u16* __restrict__ B,
                                                    OutT* __restrict__ C, int M, int N, int K) {
    __shared__ u16 lds[65536];  // 128 KiB
    const int tid = threadIdx.x;
    const int lane = tid & 63, l15 = lane & 15, l4 = lane >> 4;
    const int wave = tid >> 6;
    const int wmBase = (wave >> 2) << 7;   // 0 or 128
    const int wnBase = (wave & 3) << 6;    // 0,64,128,192
    const int waveB = wave << 10;          // wave LDS base within an 8KB load round
    const int o0 = tid * 16;

    // T1: XCD-bijective block swizzle (m204)
    const int gx = (int)gridDim.x;
    const int nwg = gx * (int)gridDim.y;
    const int orig = (int)blockIdx.y * gx + (int)blockIdx.x;
    const int qq = nwg >> 3, rr8 = nwg & 7;
    const int xcd = orig & 7, bidx = orig >> 3;
    const int swz = (xcd < rr8 ? xcd * (qq + 1) : rr8 * (qq + 1) + (xcd - rr8) * qq) + bidx;
    const int m0 = (swz / gx) << 8;
    const int n0 = (swz % gx) << 8;

    char* lb = (char*)lds;
    f32x4 acc[8][4] = {};
    bf16x8 af[8], b0, b1;

    // prologue: tile 0 -> buf0, issue order kh0(A,B) then kh1(A,B): 8 loads/thread
    STAGE(A, m0, 0, 0, 0);
    STAGE(B, n0, 65536, 0, 0);
    STAGE(A, m0, 16384, 0, 1);
    STAGE(B, n0, 65536 + 16384, 0, 1);

    const int NT = K >> 6;
#pragma unroll 1
    for (int t = 0; t < NT; ++t) {
        const int buf = t & 1, nbuf = buf ^ 1;
        const int nt = (t + 1 < NT) ? t + 1 : 0;  // tail stage redundant but harmless
        const int ab = nbuf * 32768, bb = 65536 + nbuf * 32768;
        // ---- phase 1 (k-half 0, fn 0-1) ----
        asm volatile("s_waitcnt vmcnt(4)" ::: "memory");  // kh0(t) landed; kh1(t) may fly
        __builtin_amdgcn_s_barrier();
        LDA(0, buf);
        LDB(0, 0, buf, b0);
        LDB(1, 0, buf, b1);
        STAGE(A, m0, ab, nt, 0);
        MFMA2(0, 1);
        // ---- phase 2 (k-half 0, fn 2-3) ----
        LDB(2, 0, buf, b0);
        LDB(3, 0, buf, b1);
        STAGE(B, n0, bb, nt, 0);
        MFMA2(2, 3);
        // ---- phase 3 (k-half 1, fn 0-1) ----
        asm volatile("s_waitcnt vmcnt(4)" ::: "memory");  // kh1(t) landed; kh0(t+1) may fly
        __builtin_amdgcn_s_barrier();
        LDA(1, buf);
        LDB(0, 1, buf, b0);
        LDB(1, 1, buf, b1);
        STAGE(A, m0, ab + 16384, nt, 1);
        MFMA2(0, 1);
        // ---- phase 4 (k-half 1, fn 2-3) ----
        LDB(2, 1, buf, b0);
        LDB(3, 1, buf, b1);
        STAGE(B, n0, bb + 16384, nt, 1);
        MFMA2(2, 3);
    }
    // epilogue
#pragma unroll
    for (int fm = 0; fm < 8; fm++)
#pragma unroll
        for (int fn = 0; fn < 4; fn++)
#pragma unroll
            for (int r = 0; r < 4; r++) {
                float v = acc[fm][fn][r];
                OutT sv;
                if constexpr (sizeof(OutT) == 2) sv = f2bf(v); else sv = v;
                C[(size_t)(m0 + wmBase + fm * 16 + l4 * 4 + r) * N +
                  (n0 + wnBase + fn * 16 + l15)] = sv;
            }
}

// ---------- causal GQA flash attention, work-balanced ----------
// grid (16, 32 heads): block p handles q-tiles p and 31-p (64 rows each).
// Q/K live in QKV[2048][6144]: Q at col h*128, K at col 4096+kh*128.
__global__ __launch_bounds__(256, 2) void k_attn(const u16* __restrict__ Q,
                                                 const u16* __restrict__ K,   // QKV+4096
                                                 const u16* __restrict__ Vt,
                                                 u16* __restrict__ Y) {
    __shared__ u16 kt[64 * 128];    // K tile, rows 256B, XOR-swizzled
    __shared__ u16 vt[128 * 64];    // V^T tile, rows 128B, XOR-swizzled
    __shared__ u16 pl[4 * 16 * 64]; // per-wave P, rows 128B, XOR-swizzled
    const int tid = threadIdx.x;
    const int wave = tid >> 6, lane = tid & 63;
    const int l15 = lane & 15, l4 = lane >> 4;
    const int h = blockIdx.y, kh = h >> 2;
    const float scale = 0.08838834764831845f;  // 1/sqrt(128)

    char* ktb = (char*)kt;
    char* vtb = (char*)vt;
    char* plb = (char*)pl + wave * 2048;

#pragma unroll 1
    for (int qsel = 0; qsel < 2; qsel++) {
        const int qt = qsel == 0 ? blockIdx.x : 31 - blockIdx.x;
        const int qw = qt * 64 + wave * 16;

        bf16x8 aq[4];
#pragma unroll
        for (int kf = 0; kf < 4; kf++)
            aq[kf] = *(const bf16x8*)(Q + (size_t)(qw + l15) * 6144 + h * 128 + kf * 32 + l4 * 8);

        f32x4 o[8] = {};
        float mrow[4], lrow[4];
#pragma unroll
        for (int rg = 0; rg < 4; rg++) { mrow[rg] = -1e30f; lrow[rg] = 0.f; }

        const int nkt = qt + 1;
        for (int it = 0; it < nkt; ++it) {
            const int kbase = it << 6;
#pragma unroll
            for (int p = 0; p < 4; p++) {
                int ol = wave * 4096 + p * 1024 + lane * 16;
                int key = ol >> 8, db = ol & 255;
                int src = db ^ ((key & 7) << 4);
                load_lds16((const char*)K + ((size_t)(kbase + key) * 6144 + kh * 128) * 2 + src,
                           ktb + wave * 4096 + p * 1024);
            }
#pragma unroll
            for (int p = 0; p < 4; p++) {
                int ol = wave * 4096 + p * 1024 + lane * 16;
                int d = ol >> 7, kb2 = ol & 127;
                int src = kb2 ^ ((d & 7) << 4);
                load_lds16((const char*)Vt + ((size_t)(kh * 128 + d) * 2048 + kbase) * 2 + src,
                           vtb + wave * 4096 + p * 1024);
            }
            __syncthreads();

            // S = Q K^T : 4 key-tiles
            f32x4 s[4];
#pragma unroll
            for (int tc = 0; tc < 4; tc++) {
                bf16x8 bk[4];
                const int key = tc * 16 + l15;
                const int swzk = (key & 7) << 4;
#pragma unroll
                for (int kf = 0; kf < 4; kf++)
                    bk[kf] = *(const bf16x8*)(ktb + key * 256 + ((kf * 64 + l4 * 16) ^ swzk));
                f32x4 sv = {0.f, 0.f, 0.f, 0.f};
#pragma unroll
                for (int kf = 0; kf < 4; kf++) sv = mfma16(aq[kf], bk[kf], sv);
                s[tc] = sv;
            }
            // online softmax
#pragma unroll
            for (int rg = 0; rg < 4; rg++) {
                const int qrow = qw + l4 * 4 + rg;
                float mx = -1e30f;
#pragma unroll
                for (int tc = 0; tc < 4; tc++) {
                    float v = s[tc][rg] * scale;
                    int key = kbase + tc * 16 + l15;
                    v = (key > qrow) ? -1e30f : v;
                    s[tc][rg] = v;
                    mx = fmaxf(mx, v);
                }
                mx = fmaxf(mx, __shfl_xor(mx, 1));
                mx = fmaxf(mx, __shfl_xor(mx, 2));
                mx = fmaxf(mx, __shfl_xor(mx, 4));
                mx = fmaxf(mx, __shfl_xor(mx, 8));
                const float mold = mrow[rg];
                const float mnew = fmaxf(mold, mx);
                const float corr = __expf(mold - mnew);
                mrow[rg] = mnew;
                float rsum = 0.f;
#pragma unroll
                for (int tc = 0; tc < 4; tc++) {
                    float p = __expf(s[tc][rg] - mnew);
                    s[tc][rg] = p;
                    rsum += p;
                }
                rsum += __shfl_xor(rsum, 1);
                rsum += __shfl_xor(rsum, 2);
                rsum += __shfl_xor(rsum, 4);
                rsum += __shfl_xor(rsum, 8);
                lrow[rg] = lrow[rg] * corr + rsum;
#pragma unroll
                for (int dc = 0; dc < 8; dc++) o[dc][rg] *= corr;
            }
            // P -> per-wave LDS (swizzled), bf16
#pragma unroll
            for (int rg = 0; rg < 4; rg++) {
                const int row = l4 * 4 + rg;
                const int swzp = (row & 7) << 4;
#pragma unroll
                for (int tc = 0; tc < 4; tc++) {
                    const int cb = (tc * 16 + l15) * 2;
                    *(u16*)(plb + row * 128 + (cb ^ swzp)) = f2bf(s[tc][rg]);
                }
            }
            bf16x8 pa[2];
            {
                const int row = l15;
                const int swzp = (row & 7) << 4;
#pragma unroll
                for (int kf = 0; kf < 2; kf++)
                    pa[kf] = *(const bf16x8*)(plb + row * 128 + ((kf * 64 + l4 * 16) ^ swzp));
            }
            // O += P V
#pragma unroll
            for (int dc = 0; dc < 8; dc++) {
                bf16x8 vf[2];
                const int d = dc * 16 + l15;
                const int swzv = (d & 7) << 4;
#pragma unroll
                for (int kf = 0; kf < 2; kf++)
                    vf[kf] = *(const bf16x8*)(vtb + d * 128 + ((kf * 64 + l4 * 16) ^ swzv));
                o[dc] = mfma16(pa[0], vf[0], o[dc]);
                o[dc] = mfma16(pa[1], vf[1], o[dc]);
            }
            __syncthreads();
        }
#pragma unroll
        for (int rg = 0; rg < 4; rg++) {
            const float inv = 1.f / lrow[rg];
            const int row = qw + l4 * 4 + rg;
#pragma unroll
            for (int dc = 0; dc < 8; dc++)
                Y[(size_t)row * 4096 + h * 128 + dc * 16 + l15] = f2bf(o[dc][rg] * inv);
        }
        __syncthreads();  // LDS reuse across qsel
    }
}

extern "C" void kernel_launch(void* const* d_in, const int* in_sizes, int n_in,
                              void* d_out, int out_size, void* d_ws, size_t ws_size,
                              hipStream_t stream) {
    const float* x  = (const float*)d_in[0];
    const float* rc = (const float*)d_in[1];
    const float* rs = (const float*)d_in[2];
    const float* Wq = (const float*)d_in[3];
    const float* Wk = (const float*)d_in[4];
    const float* Wv = (const float*)d_in[5];
    const float* Wo = (const float*)d_in[6];
    float* out = (float*)d_out;  // reference output dtype is float32

    char* ws = (char*)d_ws;
    u16* xb  = (u16*)(ws);                 // 16 MiB: x bf16; later reused as Y
    u16* Wt  = (u16*)(ws + 16777216);      // 48 MiB: [Wq|Wk|Wv]^T (later Wo^T)
    u16* QKV = (u16*)(ws + 67108864);      // 24 MiB: [2048][6144] = [Q|K|V]
    u16* Vtb = (u16*)(ws + 92274688);      // 4 MiB: [8][128][2048]
    u16* Y   = xb;                         // reuse (xb dead after QKV GEMM)

    // x -> bf16
    k_cvt_bf16<<<8192, 256, 0, stream>>>(x, xb, 2097152);
    // fused weight transpose: Wt rows 0..4095 = Wq^T, 4096..5119 = Wk^T, 5120..6143 = Wv^T
    k_transpose_cvt<<<dim3(128, 128), 256, 0, stream>>>(Wq, Wt, 4096, 4096);
    k_transpose_cvt<<<dim3(32, 128), 256, 0, stream>>>(Wk, Wt + (size_t)4096 * 4096, 4096, 1024);
    k_transpose_cvt<<<dim3(32, 128), 256, 0, stream>>>(Wv, Wt + (size_t)5120 * 4096, 4096, 1024);
    // QKV = x [Wq|Wk|Wv]  (256-tile 8-phase GEMM, 192 blocks)
    k_gemm256<u16><<<dim3(24, 8), 512, 0, stream>>>(xb, Wt, QKV, 2048, 6144, 4096);
    // fused RoPE over 40 heads
    k_rope2<<<20480, 256, 0, stream>>>(QKV, rc, rs);
    // V -> V^T per head
    k_transpose_v<<<dim3(64, 4, 8), 256, 0, stream>>>(QKV, Vtb);
    // attention (work-balanced pairing); Y overwrites xb region
    k_attn<<<dim3(16, 32), 256, 0, stream>>>(QKV, QKV + 4096, Vtb, Y);
    // out = y Wo  (fp32 output, 256-tile 8-phase GEMM, 128 blocks)
    k_transpose_cvt<<<dim3(128, 128), 256, 0, stream>>>(Wo, Wt, 4096, 4096);
    k_gemm256<float><<<dim3(16, 8), 512, 0, stream>>>(Y, Wt, out, 2048, 4096, 4096);
}